// Round 14
// baseline (574.285 us; speedup 1.0000x reference)
//
#include <hip/hip_runtime.h>
#include <hip/hip_bf16.h>
#include <math.h>

#define N_NODES 50000
#define N_EDGES 800000
#define IN_FEAT 32
#define EDGE_FEAT 8
#define HEADS 3
#define N_GRAPHS 64
#define NBLK_SCAN 196   // ceil(50000/256)

typedef __hip_bfloat16 bf16;

static __device__ __forceinline__ float fast_sigmoid(float x){
    return __builtin_amdgcn_rcpf(1.f + __expf(-x));
}
static __device__ __forceinline__ float fast_softplus(float x){
    return fmaxf(x, 0.f) + __logf(1.f + __expf(-fabsf(x)));
}
static __device__ __forceinline__ float lrelu02(float x){ return x > 0.f ? x : 0.2f*x; }
static __device__ __forceinline__ float b2f(bf16 h){ return __bfloat162float(h); }

// ---------------- CSR build ----------------
__global__ void k_zero_i(int* __restrict__ p, int n){
    int i = blockIdx.x*blockDim.x + threadIdx.x;
    if (i < n) p[i] = 0;
}
__global__ void k_hist(const int* __restrict__ dstv, int* __restrict__ deg){
    int e = blockIdx.x*blockDim.x + threadIdx.x;
    if (e < N_EDGES) atomicAdd(&deg[dstv[e]], 1);
}
__global__ __launch_bounds__(256) void k_scan_local(
    const int* __restrict__ deg, int* __restrict__ rowptr, int* __restrict__ bsum){
    __shared__ int sdata[256];
    int i = blockIdx.x*256 + threadIdx.x;
    int v = (i < N_NODES) ? deg[i] : 0;
    sdata[threadIdx.x] = v;
    __syncthreads();
    #pragma unroll
    for (int st = 1; st < 256; st <<= 1){
        int t = (threadIdx.x >= st) ? sdata[threadIdx.x - st] : 0;
        __syncthreads();
        sdata[threadIdx.x] += t;
        __syncthreads();
    }
    if (i < N_NODES) rowptr[i] = sdata[threadIdx.x] - v;
    if (threadIdx.x == 255) bsum[blockIdx.x] = sdata[255];
}
__global__ __launch_bounds__(256) void k_scan_bsums(
    const int* __restrict__ bsum, int* __restrict__ boff){
    __shared__ int sdata[256];
    int v = (threadIdx.x < NBLK_SCAN) ? bsum[threadIdx.x] : 0;
    sdata[threadIdx.x] = v;
    __syncthreads();
    #pragma unroll
    for (int st = 1; st < 256; st <<= 1){
        int t = (threadIdx.x >= st) ? sdata[threadIdx.x - st] : 0;
        __syncthreads();
        sdata[threadIdx.x] += t;
        __syncthreads();
    }
    if (threadIdx.x < NBLK_SCAN) boff[threadIdx.x] = sdata[threadIdx.x] - v;
}
__global__ void k_scan_add(int* __restrict__ rowptr, const int* __restrict__ boff,
                           int* __restrict__ cur){
    int i = blockIdx.x*blockDim.x + threadIdx.x;
    if (i < N_NODES){
        int r = rowptr[i] + boff[i >> 8];
        rowptr[i] = r; cur[i] = r;
    }
    if (i == 0) rowptr[N_NODES] = N_EDGES;
}
__global__ void k_scatter(const int* __restrict__ srcv, const int* __restrict__ dstv,
                          int* __restrict__ cur, int* __restrict__ esrc,
                          int* __restrict__ eord){
    int e = blockIdx.x*blockDim.x + threadIdx.x;
    if (e >= N_EDGES) return;
    int d = dstv[e];
    int pos = atomicAdd(&cur[d], 1);
    esrc[pos] = srcv[e];
    eord[pos] = e;
}

// ---------------- CGConv ----------------
// PERSISTENT; column order [AF | AS | BF | BS]: the gathered halves (BF|BS)
// share ONE aligned 128B line per node (was 2 half-wasted lines per edge).
__global__ __launch_bounds__(256) void k_pre(
    const float* __restrict__ x,
    const float* __restrict__ Wf, const float* __restrict__ bf,
    const float* __restrict__ Ws, const float* __restrict__ bs,
    bf16* __restrict__ AB)
{
    __shared__ float sC[32*128];
    for (int i = threadIdx.x; i < 32*128; i += 256){
        int k = i >> 7, j = i & 127;
        float w;
        if      (j < 32)  w = Wf[k*32 + j];             // AF
        else if (j < 64)  w = Ws[k*32 + (j-32)];        // AS
        else if (j < 96)  w = Wf[(32+k)*32 + (j-64)];   // BF
        else              w = Ws[(32+k)*32 + (j-96)];   // BS
        sC[i] = w;
    }
    __syncthreads();
    for (int idx = blockIdx.x*256 + threadIdx.x; idx < N_NODES*128; idx += gridDim.x*256){
        int n = idx >> 7, j = idx & 127;
        float a = 0.f;
        if (j < 32) a = bf[j];
        else if (j < 64) a = bs[j-32];
        const float4* xr = (const float4*)(x + (size_t)n*32);
        #pragma unroll
        for (int k4 = 0; k4 < 8; k4++){
            float4 v = xr[k4];
            int k = k4*4;
            a = fmaf(v.x, sC[(k  )*128 + j], a);
            a = fmaf(v.y, sC[(k+1)*128 + j], a);
            a = fmaf(v.z, sC[(k+2)*128 + j], a);
            a = fmaf(v.w, sC[(k+3)*128 + j], a);
        }
        AB[idx] = __float2bfloat16(a);
    }
}

// wave-per-node gather; scalarized CSR walk + edge pairing; [AF|AS|BF|BS]
// layout so each edge's gather hits exactly one 128B line; 8-edge unroll.
__global__ __launch_bounds__(256) void k_cg_gather(
    const float* __restrict__ xin, const bf16* __restrict__ AB,
    const float* __restrict__ ea,
    const int* __restrict__ rowptr, const int* __restrict__ esrc,
    const int* __restrict__ eord,
    const float* __restrict__ Wf, const float* __restrict__ Ws,
    float* __restrict__ outp)
{
    const int lane = threadIdx.x & 63;
    const int half = lane >> 5, c = lane & 31;
    const float* WzOwn  = half ? Ws : Wf;
    const float* WzSwap = half ? Wf : Ws;
    float wo[8], wx[8];
    #pragma unroll
    for (int k = 0; k < 8; k++){
        wo[k] = WzOwn[(64+k)*32+c];
        wx[k] = WzSwap[(64+k)*32+c];
    }
    const int d = __builtin_amdgcn_readfirstlane((blockIdx.x*256 + threadIdx.x) >> 6);
    if (d >= N_NODES) return;
    const int lo = rowptr[d], hi = rowptr[d+1];
    const int offOwn  = 64 + half*32 + c;        // BF (half0) / BS (half1)
    const int offSwap = 96 - half*32 + c;        // BS (half0) / BF (half1)
    const float baseOwn  = b2f(AB[d*128 + half*32 + c]);          // AF / AS
    const float baseSwap = b2f(AB[d*128 + (32 - half*32) + c]);   // AS / AF
    float acc = 0.f;

    auto mv = [&](float v, const float* w8, const float4& e0, const float4& e1) -> float {
        v = fmaf(e0.x, w8[0], v); v = fmaf(e0.y, w8[1], v);
        v = fmaf(e0.z, w8[2], v); v = fmaf(e0.w, w8[3], v);
        v = fmaf(e1.x, w8[4], v); v = fmaf(e1.y, w8[5], v);
        v = fmaf(e1.z, w8[6], v); v = fmaf(e1.w, w8[7], v);
        return v;
    };
    auto pair = [&](int i) -> float {
        int sA = __builtin_amdgcn_readfirstlane(esrc[i]);
        int sB = __builtin_amdgcn_readfirstlane(esrc[i+1]);
        int eA = __builtin_amdgcn_readfirstlane(eord[i]);
        int eB = __builtin_amdgcn_readfirstlane(eord[i+1]);
        float bA = b2f(AB[sA*128 + offOwn]);
        float bB = b2f(AB[sB*128 + offSwap]);
        const float4* epA = (const float4*)(ea + (size_t)eA*8);
        const float4* epB = (const float4*)(ea + (size_t)eB*8);
        float4 ea0 = epA[0], ea1 = epA[1];
        float4 ea2 = epB[0], ea3 = epB[1];
        float vA = mv(baseOwn  + bA, wo, ea0, ea1);
        float vB = mv(baseSwap + bB, wx, ea2, ea3);
        float xA = __shfl_xor(vA, 32, 64);
        float xB = __shfl_xor(vB, 32, 64);
        float fv = half ? vB : vA;
        float sv = half ? xB : xA;
        return fast_sigmoid(fv) * fast_softplus(sv);
    };

    int i = lo;
    for (; i + 7 < hi; i += 8){
        acc += pair(i);
        acc += pair(i+2);
        acc += pair(i+4);
        acc += pair(i+6);
    }
    for (; i + 1 < hi; i += 2)
        acc += pair(i);
    for (; i < hi; i++){
        int s = __builtin_amdgcn_readfirstlane(esrc[i]);
        int e = __builtin_amdgcn_readfirstlane(eord[i]);
        float b = b2f(AB[s*128 + offOwn]);
        const float4* ep = (const float4*)(ea + (size_t)e*8);
        float4 ea0 = ep[0], ea1 = ep[1];
        float v = mv(baseOwn + b, wo, ea0, ea1);
        float o = __shfl_xor(v, 32, 64);
        if (half == 0) acc += fast_sigmoid(v) * fast_softplus(o);
    }
    float total = acc + __shfl_xor(acc, 32, 64);
    if (half == 0) outp[d*32 + c] = fmaxf(xin[d*32 + c] + total, 0.f);
}

// ---------------- GAT ----------------
// PERSISTENT linear + fused logits (shfl reductions, no loop barrier).
template<int Ci, int Co, int NN>
__global__ __launch_bounds__(NN*Co) void k_linear_al(
    const float* __restrict__ in, const float* __restrict__ W,
    const float* __restrict__ a_src, const float* __restrict__ a_dst,
    bf16* __restrict__ out, float* __restrict__ als, float* __restrict__ ald,
    int N)
{
    const int C = Co / HEADS;
    __shared__ float sW[Ci*Co];
    for (int i = threadIdx.x; i < Ci*Co; i += NN*Co) sW[i] = W[i];
    __syncthreads();
    const int tid = threadIdx.x;
    const int nl = tid / Co, co = tid % Co;
    const float asw = a_src[co], adw = a_dst[co];
    for (int n0 = blockIdx.x*NN; n0 < N; n0 += gridDim.x*NN){
        const int n = n0 + nl;
        float a = 0.f;
        if (n < N){
            const float* row = in + (size_t)n*Ci;
            #pragma unroll
            for (int k = 0; k < Ci; k++) a = fmaf(row[k], sW[k*Co + co], a);
            out[(size_t)n*Co + co] = __float2bfloat16(a);
        }
        float s1 = a*asw, s2 = a*adw;
        #pragma unroll
        for (int off = C/2; off; off >>= 1){
            s1 += __shfl_xor(s1, off, 64);
            s2 += __shfl_xor(s2, off, 64);
        }
        if ((co & (C-1)) == 0 && n < N){
            als[n*HEADS + co/C] = s1;
            ald[n*HEADS + co/C] = s2;
        }
    }
}

// FUSED softmax+aggregation without max pass (logits O(1)); agg unrolled x8.
template<int C, int BLK>
__global__ __launch_bounds__(BLK) void k_gat_fused2(
    const bf16* __restrict__ hg, const int* __restrict__ rowptr,
    const int* __restrict__ esrc,
    const float* __restrict__ als, const float* __restrict__ ald,
    const float* __restrict__ bias, float* __restrict__ O)
{
    const int HC = HEADS*C;
    const int CH = 128;
    __shared__ float p0b[128], p1b[128], p2b[128];
    __shared__ float sred[3];
    const int d = blockIdx.x;
    const int tid = threadIdx.x;
    const int lo = rowptr[d], hi = rowptr[d+1];
    const float ad0 = ald[d*3+0], ad1 = ald[d*3+1], ad2 = ald[d*3+2];
    const int h = (tid < HC) ? tid / C : 0;
    const float* ph = (h == 0) ? p0b : (h == 1) ? p1b : p2b;
    float acc = 0.f;
    float ps0 = 0.f, ps1 = 0.f, ps2 = 0.f;
    for (int base = lo; base < hi; base += CH){
        int cnt = min(CH, hi - base);
        if (tid < 64){
            for (int j = tid; j < cnt; j += 64){
                int s = esrc[base + j];
                float p0 = __expf(lrelu02(als[s*3+0] + ad0));
                float p1 = __expf(lrelu02(als[s*3+1] + ad1));
                float p2 = __expf(lrelu02(als[s*3+2] + ad2));
                p0b[j] = p0; p1b[j] = p1; p2b[j] = p2;
                ps0 += p0; ps1 += p1; ps2 += p2;
            }
        }
        __syncthreads();
        if (tid < HC){
            int j = 0;
            for (; j + 7 < cnt; j += 8){
                int i = base + j;
                int s0 = __builtin_amdgcn_readfirstlane(esrc[i]);
                int s1 = __builtin_amdgcn_readfirstlane(esrc[i+1]);
                int s2 = __builtin_amdgcn_readfirstlane(esrc[i+2]);
                int s3 = __builtin_amdgcn_readfirstlane(esrc[i+3]);
                int s4 = __builtin_amdgcn_readfirstlane(esrc[i+4]);
                int s5 = __builtin_amdgcn_readfirstlane(esrc[i+5]);
                int s6 = __builtin_amdgcn_readfirstlane(esrc[i+6]);
                int s7 = __builtin_amdgcn_readfirstlane(esrc[i+7]);
                float g0 = b2f(hg[s0*HC + tid]);
                float g1 = b2f(hg[s1*HC + tid]);
                float g2 = b2f(hg[s2*HC + tid]);
                float g3 = b2f(hg[s3*HC + tid]);
                float g4 = b2f(hg[s4*HC + tid]);
                float g5 = b2f(hg[s5*HC + tid]);
                float g6 = b2f(hg[s6*HC + tid]);
                float g7 = b2f(hg[s7*HC + tid]);
                acc = fmaf(ph[j],   g0, acc);
                acc = fmaf(ph[j+1], g1, acc);
                acc = fmaf(ph[j+2], g2, acc);
                acc = fmaf(ph[j+3], g3, acc);
                acc = fmaf(ph[j+4], g4, acc);
                acc = fmaf(ph[j+5], g5, acc);
                acc = fmaf(ph[j+6], g6, acc);
                acc = fmaf(ph[j+7], g7, acc);
            }
            for (; j + 3 < cnt; j += 4){
                int i = base + j;
                int s0 = __builtin_amdgcn_readfirstlane(esrc[i]);
                int s1 = __builtin_amdgcn_readfirstlane(esrc[i+1]);
                int s2 = __builtin_amdgcn_readfirstlane(esrc[i+2]);
                int s3 = __builtin_amdgcn_readfirstlane(esrc[i+3]);
                float g0 = b2f(hg[s0*HC + tid]);
                float g1 = b2f(hg[s1*HC + tid]);
                float g2 = b2f(hg[s2*HC + tid]);
                float g3 = b2f(hg[s3*HC + tid]);
                acc = fmaf(ph[j],   g0, acc);
                acc = fmaf(ph[j+1], g1, acc);
                acc = fmaf(ph[j+2], g2, acc);
                acc = fmaf(ph[j+3], g3, acc);
            }
            for (; j < cnt; j++){
                int s = __builtin_amdgcn_readfirstlane(esrc[base + j]);
                acc = fmaf(ph[j], b2f(hg[s*HC + tid]), acc);
            }
        }
        __syncthreads();
    }
    if (tid < 64){
        #pragma unroll
        for (int off = 32; off; off >>= 1){
            ps0 += __shfl_xor(ps0, off, 64);
            ps1 += __shfl_xor(ps1, off, 64);
            ps2 += __shfl_xor(ps2, off, 64);
        }
        if (tid == 0){ sred[0] = ps0; sred[1] = ps1; sred[2] = ps2; }
    }
    __syncthreads();
    if (tid < HC){
        float slh = lrelu02(als[d*3+h] + ald[d*3+h]);
        float p_self = __expf(slh);
        float r = __builtin_amdgcn_rcpf(sred[h] + p_self + 1e-16f);
        float self_hg = b2f(hg[d*HC + tid]);
        O[d*HC + tid] = fmaxf(fmaf(acc + p_self*self_hg, r, 0.f) + bias[tid], 0.f);
    }
}

// ---------------- pool + MLP (fused) ----------------
__global__ __launch_bounds__(256) void k_pool_mlp(
    const float* __restrict__ O2, const int* __restrict__ batch,
    const float* __restrict__ Wl1, const float* __restrict__ bl1,
    const float* __restrict__ Wl2, const float* __restrict__ bl2,
    float* __restrict__ out){
    __shared__ int s_range[2];
    __shared__ float red[240];
    __shared__ float gm[48];
    __shared__ float g1[16];
    const int gr = blockIdx.x;
    const int tid = threadIdx.x;
    if (tid < 2){
        int key = gr + tid;
        int lo = 0, hi = N_NODES;
        while (lo < hi){ int mid = (lo+hi) >> 1; if (batch[mid] < key) lo = mid+1; else hi = mid; }
        s_range[tid] = lo;
    }
    __syncthreads();
    const int lo = s_range[0], hi = s_range[1];
    if (tid < 240){
        const int c = tid % 48, r = tid / 48;
        float a = 0.f;
        for (int n = lo + r; n < hi; n += 5) a += O2[(size_t)n*48 + c];
        red[tid] = a;
    }
    __syncthreads();
    if (tid < 48){
        float a = red[tid] + red[48+tid] + red[96+tid] + red[144+tid] + red[192+tid];
        gm[tid] = a / fmaxf((float)(hi - lo), 1.f);
    }
    __syncthreads();
    if (tid < 16){
        float a = bl1[tid];
        #pragma unroll
        for (int k = 0; k < 48; k++) a = fmaf(gm[k], Wl1[k*16 + tid], a);
        g1[tid] = fmaxf(a, 0.f);
    }
    __syncthreads();
    if (tid < 10){
        float a = bl2[tid];
        #pragma unroll
        for (int k = 0; k < 16; k++) a = fmaf(g1[k], Wl2[k*10 + tid], a);
        out[gr*10 + tid] = a;
    }
}

extern "C" void kernel_launch(void* const* d_in, const int* in_sizes, int n_in,
                              void* d_out, int out_size, void* d_ws, size_t ws_size,
                              hipStream_t stream) {
    const float* x    = (const float*)d_in[0];
    const float* ea   = (const float*)d_in[1];
    const int*   ei   = (const int*)  d_in[2];
    const int*   batch= (const int*)  d_in[3];
    const float* Wf1 = (const float*)d_in[4];  const float* bf1 = (const float*)d_in[5];
    const float* Ws1 = (const float*)d_in[6];  const float* bs1 = (const float*)d_in[7];
    const float* Wf2 = (const float*)d_in[8];  const float* bf2 = (const float*)d_in[9];
    const float* Ws2 = (const float*)d_in[10]; const float* bs2 = (const float*)d_in[11];
    const float* Wg1 = (const float*)d_in[12];
    const float* asrc1=(const float*)d_in[13]; const float* adst1=(const float*)d_in[14];
    const float* bg1 = (const float*)d_in[15];
    const float* Wg2 = (const float*)d_in[16];
    const float* asrc2=(const float*)d_in[17]; const float* adst2=(const float*)d_in[18];
    const float* bg2 = (const float*)d_in[19];
    const float* Wl1 = (const float*)d_in[20]; const float* bl1 = (const float*)d_in[21];
    const float* Wl2 = (const float*)d_in[22]; const float* bl2 = (const float*)d_in[23];
    float* out = (float*)d_out;

    const int* srcv = ei;
    const int* dstv = ei + N_EDGES;

    // ---- workspace arena (float units; lifetime overlays; ~62 MB) ----
    float* w   = (float*)d_ws;
    float* XA  = w;                  // 1.6M relu(conv1)
    float* XB  = XA + 1600000;       // 1.6M relu(conv2) = GAT1 input
    float* R2  = XB + 1600000;       // 6.4M floats: ABh/HG1h/HG2h (bf16) + O2
    float* R3  = R2 + 6400000;       // 4.8M O1 (GAT phase)
    float* ALs = R3 + 4800000;       // 150k
    float* ALd = ALs + 150000;       // 150k
    float* GM  = ALd + 150000;       // 3072 (scratch)
    int* deg    = (int*)(GM + 3072); // 50k
    int* cur    = deg + 50000;       // 50k
    int* rowptr = cur + 50000;       // 50004
    int* esrc   = rowptr + 50004;    // 800k
    int* eord   = esrc + 800000;     // 800k
    int* bsum   = eord + 800000;     // 196
    int* boff   = bsum + NBLK_SCAN;  // 196
    bf16* ABh   = (bf16*)R2;         // conv phase
    bf16* HG1h  = (bf16*)R2;         // GAT1
    bf16* HG2h  = (bf16*)R2;         // GAT2
    float* O2   = R2 + 2400000;      // disjoint from HG2h span
    float* O1   = R3;                // GAT phase
    (void)ws_size; (void)in_sizes; (void)n_in; (void)out_size;

    auto G = [](int n){ return (n + 255)/256; };

    // ---- CSR by dst ----
    k_zero_i<<<G(N_NODES), 256, 0, stream>>>(deg, N_NODES);
    k_hist<<<G(N_EDGES), 256, 0, stream>>>(dstv, deg);
    k_scan_local<<<NBLK_SCAN, 256, 0, stream>>>(deg, rowptr, bsum);
    k_scan_bsums<<<1, 256, 0, stream>>>(bsum, boff);
    k_scan_add<<<G(N_NODES), 256, 0, stream>>>(rowptr, boff, cur);
    k_scatter<<<G(N_EDGES), 256, 0, stream>>>(srcv, dstv, cur, esrc, eord);

    // ---- CGConv 1 ----
    k_pre<<<1280, 256, 0, stream>>>(x, Wf1, bf1, Ws1, bs1, ABh);
    k_cg_gather<<<(N_NODES*64)/256, 256, 0, stream>>>(x, ABh, ea, rowptr, esrc, eord, Wf1, Ws1, XA);

    // ---- CGConv 2 ----
    k_pre<<<1280, 256, 0, stream>>>(XA, Wf2, bf2, Ws2, bs2, ABh);
    k_cg_gather<<<(N_NODES*64)/256, 256, 0, stream>>>(XA, ABh, ea, rowptr, esrc, eord, Wf2, Ws2, XB);

    // ---- GATConv 1 (C=32) ----
    k_linear_al<32,96,2><<<1280, 192, 0, stream>>>(XB, Wg1, asrc1, adst1, HG1h, ALs, ALd, N_NODES);
    k_gat_fused2<32,128><<<N_NODES, 128, 0, stream>>>(HG1h, rowptr, esrc, ALs, ALd, bg1, O1);

    // ---- GATConv 2 (C=16) ----
    k_linear_al<96,48,4><<<1280, 192, 0, stream>>>(O1, Wg2, asrc2, adst2, HG2h, ALs, ALd, N_NODES);
    k_gat_fused2<16,64><<<N_NODES, 64, 0, stream>>>(HG2h, rowptr, esrc, ALs, ALd, bg2, O2);

    // ---- pool + MLP (fused) ----
    k_pool_mlp<<<N_GRAPHS, 256, 0, stream>>>(O2, batch, Wl1, bl1, Wl2, bl2, out);
}